// Round 9
// baseline (224.042 us; speedup 1.0000x reference)
//
#include <hip/hip_runtime.h>
#include <math.h>

// Problem constants (from reference): B=64, Q=900, T=128, NUM_CLASSES=13
#define B_    64
#define Q_    900
#define T_    128
#define NCLS  13
#define NCLS1 14
#define NTH   256
#define NWV   (NTH / 64)
#define NK    15          // fallback scan: col q = lane + 64*k, k<NK
#define LC    8           // per-row free-candidate list length

// Block-wide f64 sum; result valid on tid 0. All threads must call.
__device__ __forceinline__ double blockSum(double v, double* sAcc, int tid) {
#pragma unroll
    for (int off = 32; off > 0; off >>= 1) v += __shfl_down(v, off);
    if ((tid & 63) == 0) sAcc[tid >> 6] = v;
    __syncthreads();
    if (tid == 0) {
#pragma unroll
        for (int w = 1; w < NWV; ++w) v += sAcc[w];
    }
    __syncthreads();
    return v;
}

// f32 cost entry, identical op order to the jnp reference:
// (|dx|+|dy|+|dz|+|dw| summed left-to-right) - prob[lab].
__device__ __forceinline__ float costQ(const float4 p4, const float4 t4, const float pr) {
    float cb = fabsf(p4.x - t4.x);
    cb = cb + fabsf(p4.y - t4.y);
    cb = cb + fabsf(p4.z - t4.z);
    cb = cb + fabsf(p4.w - t4.w);
    return cb - pr;
}

// Sortable-uint packing: key64 = (sortable(f32 value) << 32) | column.
// u64 ordering == lexicographic (value, col) — matches np.argmin tie-break.
__device__ __forceinline__ unsigned long long packKC(float c, int col) {
    unsigned u = __float_as_uint(c);
    u = (u & 0x80000000u) ? ~u : (u | 0x80000000u);
    return ((unsigned long long)u << 32) | (unsigned)col;
}
__device__ __forceinline__ float unpackC(unsigned u) {
    u = (u & 0x80000000u) ? (u ^ 0x80000000u) : ~u;
    return __uint_as_float(u);
}

#define CSW(a, b) { const unsigned long long _lo = ((a) < (b)) ? (a) : (b); \
                    const unsigned long long _hi = ((a) < (b)) ? (b) : (a); \
                    (a) = _lo; (b) = _hi; }

// One block per image. R6-exact semantics with a sparse pop loop:
//  - per-row top-8 (cost,col) candidate lists built in registers (2 thr/row,
//    bitonic pair-merge); entry 0 doubles as row min/argmin for greedy init.
//  - greedy zero-reduced-cost init (row argmin), free columns keep v=0 forever.
//  - SSP per free row (wave 0): relax only MATCHED columns (2 slots/lane, in
//    registers); best free candidate from the current row's list (staleness
//    checked vs live matching; exact 900-col fallback if all 8 stale);
//    deferred dual updates at pass end. Packed-u64 argmins everywhere.
// Decision stream is bit-identical to R6 (same f32 exprs, same strict-<,
// same smallest-col ties) => same assignment => absmax 0.
extern "C" __global__ __launch_bounds__(NTH, 1)
void detr_hungarian_loss(const float* __restrict__ pc,    // [B,Q,14]
                         const float* __restrict__ pbx,   // [B,Q,4]
                         const int*   __restrict__ tl,    // [B,T]
                         const float* __restrict__ tbx,   // [B,T,4]
                         float* __restrict__ out)         // [1], poisoned 0xAA
{
    const int b   = blockIdx.x;
    const int tid = threadIdx.x;

    __shared__ float  sProb[Q_ * NCLS];   // softmax probs, classes 0..12
    __shared__ float  sLse[Q_];           // logsumexp per query (for CE)
    __shared__ float4 sPb4[Q_];           // predicted boxes
    __shared__ float4 sTb4[T_];           // target boxes
    __shared__ int    sLab[T_];           // target labels
    __shared__ float  sUr[T_];            // row duals (f32)
    __shared__ float  sVcol[Q_];          // column duals (free cols stay 0)
    __shared__ int    sColMatch[Q_];      // col -> row+1, 0 = free (reused as tc[])
    __shared__ int    sMatchCol[T_];      // row -> col, -1 = unmatched
    __shared__ int    sWayRow[T_];        // Dijkstra parent slot per row-slot
    __shared__ float  sCandC[T_ * LC];    // per-row top-8 costs (ascending)
    __shared__ int    sCandJ[T_ * LC];    // per-row top-8 columns
    __shared__ int    sFree[T_];
    __shared__ int    sNF;
    __shared__ int    sPred[T_];          // target t -> matched query
    __shared__ double sAcc[NWV];

    const float FINF = __builtin_inff();

    const float* pcb = pc  + (size_t)b * Q_ * NCLS1;
    const float* pbb = pbx + (size_t)b * Q_ * 4;
    const float* tbb = tbx + (size_t)b * T_ * 4;
    const int*   tlb = tl  + (size_t)b * T_;

    // ---- stage inputs + f32 softmax (same op order as jax.nn.softmax) ----
    for (int q = tid; q < Q_; q += NTH) {
        float x[NCLS1];
#pragma unroll
        for (int c = 0; c < NCLS1; ++c) x[c] = pcb[q * NCLS1 + c];
        float mx = x[0];
#pragma unroll
        for (int c = 1; c < NCLS1; ++c) mx = fmaxf(mx, x[c]);
        float ex[NCLS1];
        float sum = 0.f;
#pragma unroll
        for (int c = 0; c < NCLS1; ++c) { ex[c] = expf(x[c] - mx); sum += ex[c]; }
#pragma unroll
        for (int c = 0; c < NCLS; ++c) sProb[q * NCLS + c] = ex[c] / sum;
        sLse[q] = mx + logf(sum);
        sPb4[q] = reinterpret_cast<const float4*>(pbb)[q];
        sColMatch[q] = 0;
        sVcol[q] = 0.f;
    }
    for (int t = tid; t < T_; t += NTH) {
        sLab[t] = tlb[t];
        sTb4[t] = reinterpret_cast<const float4*>(tbb)[t];
        sMatchCol[t] = -1;
    }
    __syncthreads();

    // ---- per-row top-8 (cost,col) lists; entry 0 = row min/argmin ----
    {
        const int r    = tid >> 1;        // 0..127, two threads per row
        const int half = tid & 1;
        const float4 t4  = sTb4[r];
        const int    lab = sLab[r];
        unsigned long long L[LC];
#pragma unroll
        for (int k = 0; k < LC; ++k) L[k] = ~0ull;
        const int q0 = half * (Q_ / 2);
        for (int q = q0; q < q0 + (Q_ / 2); ++q) {
            const float c = costQ(sPb4[q], t4, sProb[q * NCLS + lab]);
            const unsigned long long key = packKC(c, q);
            if (key < L[LC - 1]) {        // sorted insert (bubble, all-register)
                unsigned long long t = key;
#pragma unroll
                for (int k = 0; k < LC; ++k) {
                    const unsigned long long lo = (L[k] < t) ? L[k] : t;
                    const unsigned long long hi = (L[k] < t) ? t : L[k];
                    L[k] = lo; t = hi;
                }
            }
        }
        // merge with partner thread (same row): keep 8 smallest of 16
        unsigned long long Bq[LC];
#pragma unroll
        for (int k = 0; k < LC; ++k) Bq[k] = __shfl_xor(L[k], 1);
#pragma unroll
        for (int k = 0; k < LC; ++k) {    // bitonic split -> lower half
            const unsigned long long o = Bq[LC - 1 - k];
            if (o < L[k]) L[k] = o;
        }
        CSW(L[0], L[4]); CSW(L[1], L[5]); CSW(L[2], L[6]); CSW(L[3], L[7]);
        CSW(L[0], L[2]); CSW(L[1], L[3]); CSW(L[4], L[6]); CSW(L[5], L[7]);
        CSW(L[0], L[1]); CSW(L[2], L[3]); CSW(L[4], L[5]); CSW(L[6], L[7]);
        if (half == 0) {
#pragma unroll
            for (int k = 0; k < LC; ++k) {
                sCandC[(r << 3) + k] = unpackC((unsigned)(L[k] >> 32));
                sCandJ[(r << 3) + k] = (int)(L[k] & 0xffffffffull);
            }
            sUr[r] = unpackC((unsigned)(L[0] >> 32));   // row min dual
        }
    }
    __syncthreads();

    // ---- greedy zero-reduced-cost assignment (serial, tiny) ----
    if (tid == 0) {
        int nfp = 0;
        for (int r = 0; r < T_; ++r) {
            const int j = sCandJ[r << 3];              // row argmin column
            if (sColMatch[j] == 0) { sColMatch[j] = r + 1; sMatchCol[r] = j; }
            else                   sFree[nfp++] = r;
        }
        sNF = nfp;
    }
    __syncthreads();

    // ============ wave 0 only: sparse deferred-dual SSP ============
    if (tid < 64) {
        const int lane = tid;
        const int nf = sNF;
        for (int fi = 0; fi < nf; ++fi) {
            const int rf = sFree[fi];
            // pass-start snapshot of this lane's two row-slots
            const int c0 = sMatchCol[lane];
            const int c1 = sMatchCol[lane + 64];
            const float4 pb0 = (c0 >= 0) ? sPb4[c0] : make_float4(0.f,0.f,0.f,0.f);
            const float4 pb1 = (c1 >= 0) ? sPb4[c1] : make_float4(0.f,0.f,0.f,0.f);
            const float vr0 = (c0 >= 0) ? sVcol[c0] : 0.f;
            const float vr1 = (c1 >= 0) ? sVcol[c1] : 0.f;
            float d0 = FINF, d1 = FINF;
            bool act0 = (c0 >= 0), act1 = (c1 >= 0);
            bool pop0 = false, pop1 = false;
            unsigned long long bestFree = ~0ull;
            int bestPar = -1;
            int curRow = rf, curPar = -1;
            float dcur = 0.f;
            unsigned long long termKey = ~0ull;

            for (int it = 0; it < 140; ++it) {
                const float  u0  = sUr[curRow];
                const float4 t4  = sTb4[curRow];
                const int    lab = sLab[curRow];
                const float base = dcur - u0;
                // relax matched slots (same f32 exprs as R6)
                if (act0) {
                    const float c   = costQ(pb0, t4, sProb[c0 * NCLS + lab]);
                    const float cur = base + (c - vr0);
                    if (cur < d0) { d0 = cur; sWayRow[lane] = curPar; }
                }
                if (act1) {
                    const float c   = costQ(pb1, t4, sProb[c1 * NCLS + lab]);
                    const float cur = base + (c - vr1);
                    if (cur < d1) { d1 = cur; sWayRow[lane + 64] = curPar; }
                }
                // pop-argmin over matched columns (packed, smallest-col ties)
                const unsigned long long k0 = act0 ? packKC(d0, c0) : ~0ull;
                const unsigned long long k1 = act1 ? packKC(d1, c1) : ~0ull;
                unsigned long long kmin = (k0 < k1) ? k0 : k1;
#pragma unroll
                for (int m = 1; m < 64; m <<= 1) {
                    const unsigned long long o = __shfl_xor(kmin, m);
                    if (o < kmin) kmin = o;
                }
                // best free candidate of curRow from its sorted list
                unsigned long long kc = ~0ull;
                if (lane < LC) {
                    const int cc = sCandJ[(curRow << 3) + lane];
                    if (sColMatch[cc] == 0)
                        kc = packKC(base + sCandC[(curRow << 3) + lane], cc);
                }
#pragma unroll
                for (int m = 1; m < LC; m <<= 1) {
                    const unsigned long long o = __shfl_xor(kc, m);
                    if (o < kc) kc = o;
                }
                kc = __shfl(kc, 0);
                if (kc == ~0ull) {        // all 8 stale: exact full free scan
                    unsigned long long f = ~0ull;
#pragma unroll
                    for (int k = 0; k < NK; ++k) {
                        const int q = (k << 6) + lane;
                        if (q < Q_ && sColMatch[q] == 0) {
                            const float c = costQ(sPb4[q], t4, sProb[q * NCLS + lab]);
                            const unsigned long long kk = packKC(base + c, q);
                            if (kk < f) f = kk;
                        }
                    }
#pragma unroll
                    for (int m = 1; m < 64; m <<= 1) {
                        const unsigned long long o = __shfl_xor(f, m);
                        if (o < f) f = o;
                    }
                    kc = f;
                }
                if (kc < bestFree) { bestFree = kc; bestPar = curPar; }
                if (bestFree < kmin) { termKey = bestFree; break; }   // free wins
                // pop the matched column
                const int pcol = (int)(kmin & 0xffffffffull);
                const int ps   = sColMatch[pcol] - 1;     // its row = next slot
                if (ps == lane)      { act0 = false; pop0 = true; }
                if (ps == lane + 64) { act1 = false; pop1 = true; }
                curRow = ps; curPar = ps;
                dcur = unpackC((unsigned)(kmin >> 32));   // exact bit round-trip
            }

            const float dT = unpackC((unsigned)(termKey >> 32));
            const int   jT = (int)(termKey & 0xffffffffull);
            // deferred dual updates (== e-maxx incremental totals)
            if (pop0) { sUr[lane]      += dT - d0; sVcol[c0] = vr0 + (d0 - dT); }
            if (pop1) { sUr[lane + 64] += dT - d1; sVcol[c1] = vr1 + (d1 - dT); }
            if (lane == 0) sUr[rf] += dT;
            __builtin_amdgcn_wave_barrier();
            if (lane == 0 && termKey != ~0ull) {   // augment along parent slots
                int col = jT, s = bestPar, guard = 0;
                while (s >= 0 && guard++ < 140) {
                    const int old = sMatchCol[s];
                    sMatchCol[s] = col; sColMatch[col] = s + 1;
                    col = old; s = sWayRow[s];
                }
                sMatchCol[rf] = col; sColMatch[col] = rf + 1;
            }
            __builtin_amdgcn_wave_barrier();
        }
    }
    __syncthreads();

    // ---- matching result: target t <-> query sMatchCol[t] ----
    for (int t = tid; t < T_; t += NTH) sPred[t] = sMatchCol[t];
    int* sTc = sColMatch;                 // reuse as per-query CE class
    for (int q = tid; q < Q_; q += NTH) sTc[q] = NCLS;
    __syncthreads();
    for (int t = tid; t < T_; t += NTH) sTc[sPred[t]] = sLab[t];  // sPred distinct
    __syncthreads();

    // ---- weighted CE over all queries ----
    double swn = 0.0, sw = 0.0;
    for (int q = tid; q < Q_; q += NTH) {
        const int   c   = sTc[q];
        const float xv  = pcb[q * NCLS1 + c];
        const float nll = sLse[q] - xv;              // -log_softmax[tc]
        const double w  = (c == NCLS) ? (double)0.05f : 1.0;
        swn += w * (double)nll;
        sw  += w;
    }

    // ---- bbox L1 + GIoU over matched pairs ----
    double l1s = 0.0, gs = 0.0;
    for (int t = tid; t < T_; t += NTH) {
        const int q = sPred[t];
        const float4 p4 = sPb4[q];
        const float4 t4 = sTb4[t];
        l1s += (double)fabsf(p4.x - t4.x) + (double)fabsf(p4.y - t4.y)
             + (double)fabsf(p4.z - t4.z) + (double)fabsf(p4.w - t4.w);
        const float ax1 = p4.x - 0.5f * p4.z, ay1 = p4.y - 0.5f * p4.w;
        const float ax2 = p4.x + 0.5f * p4.z, ay2 = p4.y + 0.5f * p4.w;
        const float bx1 = t4.x - 0.5f * t4.z, by1 = t4.y - 0.5f * t4.w;
        const float bx2 = t4.x + 0.5f * t4.z, by2 = t4.y + 0.5f * t4.w;
        const double a1 = (double)(ax2 - ax1) * (double)(ay2 - ay1);
        const double a2 = (double)(bx2 - bx1) * (double)(by2 - by1);
        const double ltx = fmax((double)ax1, (double)bx1);
        const double lty = fmax((double)ay1, (double)by1);
        const double rbx = fmin((double)ax2, (double)bx2);
        const double rby = fmin((double)ay2, (double)by2);
        const double iw = fmax(rbx - ltx, 0.0), ih = fmax(rby - lty, 0.0);
        const double inter = iw * ih;
        const double uni   = a1 + a2 - inter;
        const double iou   = inter / uni;
        const double cx1 = fmin((double)ax1, (double)bx1);
        const double cy1 = fmin((double)ay1, (double)by1);
        const double cx2 = fmax((double)ax2, (double)bx2);
        const double cy2 = fmax((double)ay2, (double)by2);
        const double ac  = (cx2 - cx1) * (cy2 - cy1);
        const double giou = iou - (ac - uni) / ac;
        gs += 1.0 - giou;
    }

    const double swnT = blockSum(swn, sAcc, tid);
    const double swT  = blockSum(sw,  sAcc, tid);
    const double l1T  = blockSum(l1s, sAcc, tid);
    const double gsT  = blockSum(gs,  sAcc, tid);
    if (tid == 0) {
        const double cls = swnT / swT;
        const double bb  = 5.0 * (l1T / (double)(T_ * 4)) + 2.0 * (gsT / (double)T_);
        const double mine = (cls + bb) / 8192.0;
        // fused finalize: CAS converts the 0xAA poison to 0.0 exactly once
        // (each block CASes before its own add; no spin), then atomic f32 sum.
        atomicCAS((unsigned int*)out, 0xAAAAAAAAu, 0u);
        atomicAdd(out, (float)mine);
    }
}

extern "C" void kernel_launch(void* const* d_in, const int* in_sizes, int n_in,
                              void* d_out, int out_size, void* d_ws, size_t ws_size,
                              hipStream_t stream) {
    const float* pc  = (const float*)d_in[0];   // predicted_class [64,900,14]
    const float* pbx = (const float*)d_in[1];   // predicted_bbox  [64,900,4]
    const int*   tl  = (const int*)  d_in[2];   // target_labels   [64,128]
    const float* tbx = (const float*)d_in[3];   // target_boxes    [64,128,4]
    (void)in_sizes; (void)n_in; (void)out_size; (void)d_ws; (void)ws_size;

    detr_hungarian_loss<<<dim3(B_), dim3(NTH), 0, stream>>>(pc, pbx, tl, tbx,
                                                            (float*)d_out);
}

// Round 10
// 213.618 us; speedup vs baseline: 1.0488x; 1.0488x over previous
//
#include <hip/hip_runtime.h>
#include <math.h>

// Problem constants (from reference): B=64, Q=900, T=128, NUM_CLASSES=13
#define B_    64
#define Q_    900
#define T_    128
#define NCLS  13
#define NCLS1 14
#define NTH   256
#define NWV   (NTH / 64)
#define NK    15          // fallback kernel: col q = lane + 64*k
#define CMS   1024        // cost-matrix row stride (padded)
#define NKC   16          // CM kernel: cols per lane (contiguous), col = lane*16+k

// Block-wide f64 sum; result valid on tid 0. All threads must call.
__device__ __forceinline__ double blockSum(double v, double* sAcc, int tid) {
#pragma unroll
    for (int off = 32; off > 0; off >>= 1) v += __shfl_down(v, off);
    if ((tid & 63) == 0) sAcc[tid >> 6] = v;
    __syncthreads();
    if (tid == 0) {
#pragma unroll
        for (int w = 1; w < NWV; ++w) v += sAcc[w];
    }
    __syncthreads();
    return v;
}

// f32 cost entry, identical op order to the jnp reference:
// (|dx|+|dy|+|dz|+|dw| summed left-to-right) - prob[lab].
__device__ __forceinline__ float costQ(const float4 p4, const float4 t4, const float pr) {
    float cb = fabsf(p4.x - t4.x);
    cb = cb + fabsf(p4.y - t4.y);
    cb = cb + fabsf(p4.z - t4.z);
    cb = cb + fabsf(p4.w - t4.w);
    return cb - pr;
}

// Sortable-uint packing: key64 = (sortable(f32) << 32) | col.
// u64 order == lexicographic (value, col) == np.argmin tie-break. Lossless
// round-trip (verified R9, absmax 0).
__device__ __forceinline__ unsigned long long packKC(float c, int col) {
    unsigned u = __float_as_uint(c);
    u = (u & 0x80000000u) ? ~u : (u | 0x80000000u);
    return ((unsigned long long)u << 32) | (unsigned)col;
}
__device__ __forceinline__ float unpackC(unsigned u) {
    u = (u & 0x80000000u) ? (u ^ 0x80000000u) : ~u;
    return __uint_as_float(u);
}

// ============================ CM-path kernel ============================
// R6's exact decision stream (same f32 expressions, same association
// base + (cost - v[k]), strict-< updates, (value,col)-lexicographic argmin),
// with: cost matrix in global memory (built in parallel, bit-identical
// values), way[] in registers flushed per pass, duals/matching cached in
// registers with shuffle broadcast.
extern "C" __global__ __launch_bounds__(NTH, 1)
void detr_cm(const float* __restrict__ pc, const float* __restrict__ pbx,
             const int* __restrict__ tl, const float* __restrict__ tbx,
             float* __restrict__ cmBase, float* __restrict__ out)
{
    const int b   = blockIdx.x;
    const int tid = threadIdx.x;
    float* cm = cmBase + (size_t)b * T_ * CMS;

    __shared__ float  sProb[Q_ * NCLS];
    __shared__ float  sLse[Q_];
    __shared__ float4 sPb4[Q_];
    __shared__ float4 sTb4[T_];
    __shared__ int    sLab[T_];
    __shared__ float  sUr[T_];
    __shared__ float  sVcol[Q_];
    __shared__ int    sP[Q_];            // col -> row+1, 0 = free
    __shared__ int    sWay[Q_];          // per-pass parent cols; reused as tc[]
    __shared__ int    sAmin[T_];
    __shared__ int    sFree[T_];
    __shared__ int    sNF;
    __shared__ int    sPopC[200];
    __shared__ float  sPopD[200];
    __shared__ int    sPred[T_];
    __shared__ double sAcc[NWV];

    const float FINF = __builtin_inff();

    const float* pcb = pc  + (size_t)b * Q_ * NCLS1;
    const float* pbb = pbx + (size_t)b * Q_ * 4;
    const float* tbb = tbx + (size_t)b * T_ * 4;
    const int*   tlb = tl  + (size_t)b * T_;

    // ---- stage inputs + f32 softmax ----
    for (int q = tid; q < Q_; q += NTH) {
        float x[NCLS1];
#pragma unroll
        for (int c = 0; c < NCLS1; ++c) x[c] = pcb[q * NCLS1 + c];
        float mx = x[0];
#pragma unroll
        for (int c = 1; c < NCLS1; ++c) mx = fmaxf(mx, x[c]);
        float ex[NCLS1];
        float sum = 0.f;
#pragma unroll
        for (int c = 0; c < NCLS1; ++c) { ex[c] = expf(x[c] - mx); sum += ex[c]; }
#pragma unroll
        for (int c = 0; c < NCLS; ++c) sProb[q * NCLS + c] = ex[c] / sum;
        sLse[q] = mx + logf(sum);
        sPb4[q] = reinterpret_cast<const float4*>(pbb)[q];
        sP[q] = 0;
        sVcol[q] = 0.f;
    }
    for (int t = tid; t < T_; t += NTH) {
        sLab[t] = tlb[t];
        sTb4[t] = reinterpret_cast<const float4*>(tbb)[t];
    }
    __syncthreads();

    // ---- build cost matrix (bit-identical costQ values; pad = 3e38) ----
    for (int g = tid; g < (T_ * CMS) / 4; g += NTH) {
        const int idx = g << 2;
        const int r   = idx >> 10;
        const int c0  = idx & (CMS - 1);
        const float4 t4  = sTb4[r];
        const int    lab = sLab[r];
        float o[4];
#pragma unroll
        for (int u = 0; u < 4; ++u) {
            const int c = c0 + u;
            o[u] = 3.0e38f;
            if (c < Q_) o[u] = costQ(sPb4[c], t4, sProb[c * NCLS + lab]);
        }
        *reinterpret_cast<float4*>(cm + idx) = make_float4(o[0], o[1], o[2], o[3]);
    }
    __syncthreads();

    // ---- phase 1: row minima + argmin col (same scan order as R6) ----
    {
        const int r    = tid >> 1;
        const int half = tid & 1;
        const float* row = cm + (r << 10);
        float bv = FINF;
        int   bj = Q_;
        const int q0 = half * (Q_ / 2);
        for (int q = q0; q < q0 + (Q_ / 2); ++q) {
            const float c = row[q];
            if (c < bv) { bv = c; bj = q; }
        }
        const float ov = __shfl_xor(bv, 1);
        const int   oj = __shfl_xor(bj, 1);
        if (ov < bv || (ov == bv && oj < bj)) { bv = ov; bj = oj; }
        if (half == 0) { sUr[r] = bv; sAmin[r] = bj; }
    }
    __syncthreads();

    // ---- greedy zero-reduced-cost assignment (R6-identical) ----
    if (tid == 0) {
        int nf = 0;
        for (int r = 0; r < T_; ++r) {
            const int j = sAmin[r];
            if (sP[j] == 0) sP[j] = r + 1;
            else            sFree[nf++] = r;
        }
        sNF = nf;
    }
    __syncthreads();

    // ============ wave 0: deferred-dual SSP, register-cached state ========
    if (tid < 64) {
        const int lane = tid;
        const int colBase = lane << 4;
        const unsigned validMask =
            (lane < 56) ? 0xFFFFu : ((lane == 56) ? 0x000Fu : 0u);
        float v[NKC];                    // column duals (cached)
        int   cmr[NKC];                  // col -> row+1 (cached)
#pragma unroll
        for (int k = 0; k < NKC; ++k) {
            const bool real = (validMask >> k) & 1u;
            v[k]   = 0.f;
            cmr[k] = real ? sP[colBase + k] : 0;
        }
        float ur0 = sUr[lane], ur1 = sUr[lane + 64];
        const int nf = sNF;

        for (int fi = 0; fi < nf; ++fi) {
            const int rf = sFree[fi];
            float minv[NKC];
            int   way[NKC];
#pragma unroll
            for (int k = 0; k < NKC; ++k) { minv[k] = FINF; way[k] = -2; }
            unsigned usedM = ~validMask & 0xFFFFu;
            int   curRow = rf, jprev = -1;
            float dcur = 0.f;
            int   npop = 0, jT = -1;
            float dT = 0.f;

            for (int it = 0; it < 200; ++it) {
                // u0 via owner-lane shuffle (cache valid: duals frozen in-pass)
                const int   h   = curRow >> 6;
                const float myu = h ? ur1 : ur0;
                const float u0  = __shfl(myu, curRow & 63);
                const float base = dcur - u0;
                // CM row chunk: 4x dwordx4, L2-resident
                const float* rp = cm + (curRow << 10) + colBase;
                float ld[NKC];
                *reinterpret_cast<float4*>(ld + 0)  = *reinterpret_cast<const float4*>(rp + 0);
                *reinterpret_cast<float4*>(ld + 4)  = *reinterpret_cast<const float4*>(rp + 4);
                *reinterpret_cast<float4*>(ld + 8)  = *reinterpret_cast<const float4*>(rp + 8);
                *reinterpret_cast<float4*>(ld + 12) = *reinterpret_cast<const float4*>(rp + 12);

                float bestv = FINF;
                int   bestq = 1 << 29;
#pragma unroll
                for (int k = 0; k < NKC; ++k) {
                    if (!((usedM >> k) & 1u)) {
                        const float t   = ld[k] - v[k];       // cost - v[k]
                        const float cur = base + t;           // R6 association
                        if (cur < minv[k]) { minv[k] = cur; way[k] = jprev; }
                        if (minv[k] < bestv) { bestv = minv[k]; bestq = colBase + k; }
                    }
                }
                unsigned long long kk = packKC(bestv, bestq);
#pragma unroll
                for (int m = 1; m < 64; m <<= 1) {
                    const unsigned long long o = __shfl_xor(kk, m);
                    if (o < kk) kk = o;
                }
                const int   pq = (int)(kk & 0xffffffffull);
                const float pv = unpackC((unsigned)(kk >> 32));
                // resolve matched-row via register cache + shuffle
                const int ok2 = pq >> 4, ks = pq & 15;
                int val = 0;
#pragma unroll
                for (int k = 0; k < NKC; ++k) val = (k == ks) ? cmr[k] : val;
                const int rowm = __shfl(val, ok2);
                if (rowm == 0) { dT = pv; jT = pq; break; }   // free col: done
                if (lane == ok2) usedM |= 1u << ks;           // freeze popped
                if (lane == 0) { sPopC[npop] = pq; sPopD[npop] = pv; }
                ++npop;
                jprev = pq; curRow = rowm - 1; dcur = pv;
            }

            // flush way regs (augment only reads cols improved this pass)
#pragma unroll
            for (int k = 0; k < NKC; ++k) {
                if ((validMask >> k) & 1u) sWay[colBase + k] = way[k];
            }
            // deferred dual updates (pre-augment; rows/cols distinct)
            for (int e = lane; e < npop; e += 64) {
                const int   c = sPopC[e];
                const float d = sPopD[e];
                const int row = sP[c] - 1;
                sUr[row]  += dT - d;
                sVcol[c]  += d - dT;
            }
            if (lane == 0) sUr[rf] += dT;
            __builtin_amdgcn_wave_barrier();
            if (lane == 0 && jT >= 0) {                       // augment
                int jj = jT, guard = 0;
                while (guard++ < 200) {
                    const int jp = sWay[jj];
                    if (jp < 0) { sP[jj] = rf + 1; break; }
                    sP[jj] = sP[jp];
                    jj = jp;
                }
            }
            __builtin_amdgcn_wave_barrier();
            // refresh register caches
#pragma unroll
            for (int k = 0; k < NKC; ++k) {
                if ((validMask >> k) & 1u) {
                    v[k]   = sVcol[colBase + k];
                    cmr[k] = sP[colBase + k];
                }
            }
            ur0 = sUr[lane]; ur1 = sUr[lane + 64];
            __builtin_amdgcn_wave_barrier();
        }
    }
    __syncthreads();

    // ---- extract matching ----
    for (int q = tid; q < Q_; q += NTH) {
        const int pi = sP[q];
        if (pi > 0) sPred[pi - 1] = q;
    }
    __syncthreads();
    int* sTc = sWay;
    for (int q = tid; q < Q_; q += NTH) sTc[q] = NCLS;
    __syncthreads();
    for (int t = tid; t < T_; t += NTH) sTc[sPred[t]] = sLab[t];
    __syncthreads();

    // ---- weighted CE ----
    double swn = 0.0, sw = 0.0;
    for (int q = tid; q < Q_; q += NTH) {
        const int   c   = sTc[q];
        const float xv  = pcb[q * NCLS1 + c];
        const float nll = sLse[q] - xv;
        const double w  = (c == NCLS) ? (double)0.05f : 1.0;
        swn += w * (double)nll;
        sw  += w;
    }
    // ---- bbox L1 + GIoU ----
    double l1s = 0.0, gs = 0.0;
    for (int t = tid; t < T_; t += NTH) {
        const int q = sPred[t];
        const float4 p4 = sPb4[q];
        const float4 t4 = sTb4[t];
        l1s += (double)fabsf(p4.x - t4.x) + (double)fabsf(p4.y - t4.y)
             + (double)fabsf(p4.z - t4.z) + (double)fabsf(p4.w - t4.w);
        const float ax1 = p4.x - 0.5f * p4.z, ay1 = p4.y - 0.5f * p4.w;
        const float ax2 = p4.x + 0.5f * p4.z, ay2 = p4.y + 0.5f * p4.w;
        const float bx1 = t4.x - 0.5f * t4.z, by1 = t4.y - 0.5f * t4.w;
        const float bx2 = t4.x + 0.5f * t4.z, by2 = t4.y + 0.5f * t4.w;
        const double a1 = (double)(ax2 - ax1) * (double)(ay2 - ay1);
        const double a2 = (double)(bx2 - bx1) * (double)(by2 - by1);
        const double ltx = fmax((double)ax1, (double)bx1);
        const double lty = fmax((double)ay1, (double)by1);
        const double rbx = fmin((double)ax2, (double)bx2);
        const double rby = fmin((double)ay2, (double)by2);
        const double iw = fmax(rbx - ltx, 0.0), ih = fmax(rby - lty, 0.0);
        const double inter = iw * ih;
        const double uni   = a1 + a2 - inter;
        const double iou   = inter / uni;
        const double cx1 = fmin((double)ax1, (double)bx1);
        const double cy1 = fmin((double)ay1, (double)by1);
        const double cx2 = fmax((double)ax2, (double)bx2);
        const double cy2 = fmax((double)ay2, (double)by2);
        const double ac  = (cx2 - cx1) * (cy2 - cy1);
        const double giou = iou - (ac - uni) / ac;
        gs += 1.0 - giou;
    }
    const double swnT = blockSum(swn, sAcc, tid);
    const double swT  = blockSum(sw,  sAcc, tid);
    const double l1T  = blockSum(l1s, sAcc, tid);
    const double gsT  = blockSum(gs,  sAcc, tid);
    if (tid == 0) {
        const double cls = swnT / swT;
        const double bb  = 5.0 * (l1T / (double)(T_ * 4)) + 2.0 * (gsT / (double)T_);
        const double mine = (cls + bb) / 8192.0;
        atomicCAS((unsigned int*)out, 0xAAAAAAAAu, 0u);
        atomicAdd(out, (float)mine);
    }
}

// ===================== fallback: R6 kernel verbatim =====================
extern "C" __global__ __launch_bounds__(NTH, 1)
void detr_fb(const float* __restrict__ pc, const float* __restrict__ pbx,
             const int* __restrict__ tl, const float* __restrict__ tbx,
             float* __restrict__ out)
{
    const int b   = blockIdx.x;
    const int tid = threadIdx.x;
    __shared__ float  sProb[Q_ * NCLS];
    __shared__ float  sLse[Q_];
    __shared__ float4 sPb4[Q_];
    __shared__ float4 sTb4[T_];
    __shared__ int    sLab[T_];
    __shared__ float  sU[T_];
    __shared__ int    sP[Q_];
    __shared__ int    sWay[Q_];
    __shared__ int    sAmin[T_];
    __shared__ int    sFree[T_];
    __shared__ int    sNF;
    __shared__ int    sPred[T_];
    __shared__ double sAcc[NWV];
    const float FINF = __builtin_inff();
    const float* pcb = pc  + (size_t)b * Q_ * NCLS1;
    const float* pbb = pbx + (size_t)b * Q_ * 4;
    const float* tbb = tbx + (size_t)b * T_ * 4;
    const int*   tlb = tl  + (size_t)b * T_;
    for (int q = tid; q < Q_; q += NTH) {
        float x[NCLS1];
#pragma unroll
        for (int c = 0; c < NCLS1; ++c) x[c] = pcb[q * NCLS1 + c];
        float mx = x[0];
#pragma unroll
        for (int c = 1; c < NCLS1; ++c) mx = fmaxf(mx, x[c]);
        float ex[NCLS1]; float sum = 0.f;
#pragma unroll
        for (int c = 0; c < NCLS1; ++c) { ex[c] = expf(x[c] - mx); sum += ex[c]; }
#pragma unroll
        for (int c = 0; c < NCLS; ++c) sProb[q * NCLS + c] = ex[c] / sum;
        sLse[q] = mx + logf(sum);
        sPb4[q] = reinterpret_cast<const float4*>(pbb)[q];
        sP[q] = 0;
    }
    for (int t = tid; t < T_; t += NTH) {
        sLab[t] = tlb[t];
        sTb4[t] = reinterpret_cast<const float4*>(tbb)[t];
    }
    __syncthreads();
    {
        const int r = tid >> 1, half = tid & 1;
        const float4 t4 = sTb4[r]; const int lab = sLab[r];
        float bv = FINF; int bj = Q_;
        const int q0 = half * (Q_ / 2);
        for (int q = q0; q < q0 + (Q_ / 2); ++q) {
            const float c = costQ(sPb4[q], t4, sProb[q * NCLS + lab]);
            if (c < bv) { bv = c; bj = q; }
        }
        const float ov = __shfl_xor(bv, 1); const int oj = __shfl_xor(bj, 1);
        if (ov < bv || (ov == bv && oj < bj)) { bv = ov; bj = oj; }
        if (half == 0) { sU[r] = bv; sAmin[r] = bj; }
    }
    __syncthreads();
    if (tid == 0) {
        int nf = 0;
        for (int r = 0; r < T_; ++r) {
            const int j = sAmin[r];
            if (sP[j] == 0) sP[j] = r + 1; else sFree[nf++] = r;
        }
        sNF = nf;
    }
    __syncthreads();
    if (tid < 64) {
        const int lane = tid;
        const unsigned validMask = (lane < (Q_ - 64 * (NK - 1))) ? ((1u << NK) - 1u)
                                                                 : ((1u << (NK - 1)) - 1u);
        float4 pbr[NK]; float v[NK];
#pragma unroll
        for (int k = 0; k < NK; ++k) {
            const int q = (k << 6) + lane;
            pbr[k] = (q < Q_) ? sPb4[q] : make_float4(0.f, 0.f, 0.f, 0.f);
            v[k] = 0.f;
        }
        const int nf = sNF;
        for (int fi = 0; fi < nf; ++fi) {
            const int rf = sFree[fi];
            float minv[NK];
#pragma unroll
            for (int k = 0; k < NK; ++k) minv[k] = FINF;
            unsigned usedM = ~validMask, poppedM = 0;
            int i0row = rf; float dcur = 0.f; int jprev = -1;
            float dT = 0.f; int jT = -1;
            for (int it = 0; it < 200; ++it) {
                const float u0 = sU[i0row];
                const float4 t4 = sTb4[i0row];
                const int lab = sLab[i0row];
                const float base = dcur - u0;
                float bestv = FINF; int bestq = 1 << 29;
#pragma unroll
                for (int k = 0; k < NK; ++k) {
                    if (!((usedM >> k) & 1u)) {
                        const int q = (k << 6) + lane;
                        const float cost = costQ(pbr[k], t4, sProb[q * NCLS + lab]);
                        const float cur = base + (cost - v[k]);
                        if (cur < minv[k]) { minv[k] = cur; sWay[q] = jprev; }
                        if (minv[k] < bestv) { bestv = minv[k]; bestq = q; }
                    }
                }
#pragma unroll
                for (int m = 1; m < 64; m <<= 1) {
                    const float ov = __shfl_xor(bestv, m);
                    const int oq = __shfl_xor(bestq, m);
                    if (ov < bestv || (ov == bestv && oq < bestq)) { bestv = ov; bestq = oq; }
                }
                if ((bestq & 63) == lane) usedM |= 1u << (bestq >> 6);
                const int rowm = sP[bestq];
                __builtin_amdgcn_wave_barrier();
                if (rowm == 0) { dT = bestv; jT = bestq; break; }
                if ((bestq & 63) == lane) poppedM |= 1u << (bestq >> 6);
                jprev = bestq; i0row = rowm - 1; dcur = bestv;
            }
#pragma unroll
            for (int k = 0; k < NK; ++k) {
                if ((poppedM >> k) & 1u) {
                    const int q = (k << 6) + lane;
                    const int row = sP[q] - 1;
                    sU[row] += dT - minv[k];
                    v[k]    += minv[k] - dT;
                }
            }
            if (lane == 0) sU[rf] += dT;
            __builtin_amdgcn_wave_barrier();
            if (lane == 0 && jT >= 0) {
                int jj = jT, guard = 0;
                while (guard++ < 200) {
                    const int jp = sWay[jj];
                    if (jp < 0) { sP[jj] = rf + 1; break; }
                    sP[jj] = sP[jp]; jj = jp;
                }
            }
            __builtin_amdgcn_wave_barrier();
        }
    }
    __syncthreads();
    for (int q = tid; q < Q_; q += NTH) {
        const int pi = sP[q];
        if (pi > 0) sPred[pi - 1] = q;
    }
    __syncthreads();
    int* sTc = sWay;
    for (int q = tid; q < Q_; q += NTH) sTc[q] = NCLS;
    __syncthreads();
    for (int t = tid; t < T_; t += NTH) sTc[sPred[t]] = sLab[t];
    __syncthreads();
    double swn = 0.0, sw = 0.0;
    for (int q = tid; q < Q_; q += NTH) {
        const int c = sTc[q];
        const float xv = pcb[q * NCLS1 + c];
        const float nll = sLse[q] - xv;
        const double w = (c == NCLS) ? (double)0.05f : 1.0;
        swn += w * (double)nll; sw += w;
    }
    double l1s = 0.0, gs = 0.0;
    for (int t = tid; t < T_; t += NTH) {
        const int q = sPred[t];
        const float4 p4 = sPb4[q]; const float4 t4 = sTb4[t];
        l1s += (double)fabsf(p4.x - t4.x) + (double)fabsf(p4.y - t4.y)
             + (double)fabsf(p4.z - t4.z) + (double)fabsf(p4.w - t4.w);
        const float ax1 = p4.x - 0.5f * p4.z, ay1 = p4.y - 0.5f * p4.w;
        const float ax2 = p4.x + 0.5f * p4.z, ay2 = p4.y + 0.5f * p4.w;
        const float bx1 = t4.x - 0.5f * t4.z, by1 = t4.y - 0.5f * t4.w;
        const float bx2 = t4.x + 0.5f * t4.z, by2 = t4.y + 0.5f * t4.w;
        const double a1 = (double)(ax2 - ax1) * (double)(ay2 - ay1);
        const double a2 = (double)(bx2 - bx1) * (double)(by2 - by1);
        const double ltx = fmax((double)ax1, (double)bx1);
        const double lty = fmax((double)ay1, (double)by1);
        const double rbx = fmin((double)ax2, (double)bx2);
        const double rby = fmin((double)ay2, (double)by2);
        const double iw = fmax(rbx - ltx, 0.0), ih = fmax(rby - lty, 0.0);
        const double inter = iw * ih;
        const double uni = a1 + a2 - inter;
        const double iou = inter / uni;
        const double cx1 = fmin((double)ax1, (double)bx1);
        const double cy1 = fmin((double)ay1, (double)by1);
        const double cx2 = fmax((double)ax2, (double)bx2);
        const double cy2 = fmax((double)ay2, (double)by2);
        const double ac = (cx2 - cx1) * (cy2 - cy1);
        const double giou = iou - (ac - uni) / ac;
        gs += 1.0 - giou;
    }
    const double swnT = blockSum(swn, sAcc, tid);
    const double swT  = blockSum(sw,  sAcc, tid);
    const double l1T  = blockSum(l1s, sAcc, tid);
    const double gsT  = blockSum(gs,  sAcc, tid);
    if (tid == 0) {
        const double cls = swnT / swT;
        const double bb = 5.0 * (l1T / (double)(T_ * 4)) + 2.0 * (gsT / (double)T_);
        const double mine = (cls + bb) / 8192.0;
        atomicCAS((unsigned int*)out, 0xAAAAAAAAu, 0u);
        atomicAdd(out, (float)mine);
    }
}

extern "C" void kernel_launch(void* const* d_in, const int* in_sizes, int n_in,
                              void* d_out, int out_size, void* d_ws, size_t ws_size,
                              hipStream_t stream) {
    const float* pc  = (const float*)d_in[0];   // predicted_class [64,900,14]
    const float* pbx = (const float*)d_in[1];   // predicted_bbox  [64,900,4]
    const int*   tl  = (const int*)  d_in[2];   // target_labels   [64,128]
    const float* tbx = (const float*)d_in[3];   // target_boxes    [64,128,4]
    (void)in_sizes; (void)n_in; (void)out_size;

    const size_t need = (size_t)B_ * T_ * CMS * sizeof(float);   // 32 MiB
    if (ws_size >= need) {
        detr_cm<<<dim3(B_), dim3(NTH), 0, stream>>>(pc, pbx, tl, tbx,
                                                    (float*)d_ws, (float*)d_out);
    } else {
        detr_fb<<<dim3(B_), dim3(NTH), 0, stream>>>(pc, pbx, tl, tbx,
                                                    (float*)d_out);
    }
}

// Round 11
// 162.740 us; speedup vs baseline: 1.3767x; 1.3126x over previous
//
#include <hip/hip_runtime.h>
#include <math.h>

// Problem constants (from reference): B=64, Q=900, T=128, NUM_CLASSES=13
#define B_    64
#define Q_    900
#define T_    128
#define NCLS  13
#define NCLS1 14
#define NTH   256
#define NWV   (NTH / 64)
#define NK    15          // wave0 scan: col q = lane + 64*k, k<NK

// Block-wide f64 sum; result valid on tid 0. All threads must call.
__device__ __forceinline__ double blockSum(double v, double* sAcc, int tid) {
#pragma unroll
    for (int off = 32; off > 0; off >>= 1) v += __shfl_down(v, off);
    if ((tid & 63) == 0) sAcc[tid >> 6] = v;
    __syncthreads();
    if (tid == 0) {
#pragma unroll
        for (int w = 1; w < NWV; ++w) v += sAcc[w];
    }
    __syncthreads();
    return v;
}

// f32 cost entry, identical op order to the jnp reference:
// (|dx|+|dy|+|dz|+|dw| summed left-to-right) - prob[lab].
__device__ __forceinline__ float costQ(const float4 p4, const float4 t4, const float pr) {
    float cb = fabsf(p4.x - t4.x);
    cb = cb + fabsf(p4.y - t4.y);
    cb = cb + fabsf(p4.z - t4.z);
    cb = cb + fabsf(p4.w - t4.w);
    return cb - pr;
}

// ---- DPP full-wave min reductions (GCN/CDNA row_shr + row_bcast chain) ----
// Result returned uniform to all lanes via readlane(63). bound_ctrl=false:
// lanes with invalid source keep `old` (= +INF / INT_MAX identity).
#define DPP_ROW_SHR1 0x111
#define DPP_ROW_SHR2 0x112
#define DPP_ROW_SHR4 0x114
#define DPP_ROW_SHR8 0x118
#define DPP_BCAST15  0x142
#define DPP_BCAST31  0x143

__device__ __forceinline__ float waveMinF32(float x) {
    const int INFI = 0x7f800000;                       // +inf bits
    float f = x;
#define MRED(C) { const int o = __builtin_amdgcn_update_dpp(INFI, __float_as_int(f), C, 0xf, 0xf, false); \
                  f = fminf(f, __int_as_float(o)); }
    MRED(DPP_ROW_SHR1) MRED(DPP_ROW_SHR2) MRED(DPP_ROW_SHR4) MRED(DPP_ROW_SHR8)
    MRED(DPP_BCAST15)  MRED(DPP_BCAST31)
#undef MRED
    return __int_as_float(__builtin_amdgcn_readlane(__float_as_int(f), 63));
}

__device__ __forceinline__ int waveMinI32(int x) {
    int f = x;
#define MRED(C) { const int o = __builtin_amdgcn_update_dpp(0x7fffffff, f, C, 0xf, 0xf, false); \
                  f = (o < f) ? o : f; }
    MRED(DPP_ROW_SHR1) MRED(DPP_ROW_SHR2) MRED(DPP_ROW_SHR4) MRED(DPP_ROW_SHR8)
    MRED(DPP_BCAST15)  MRED(DPP_BCAST31)
#undef MRED
    return __builtin_amdgcn_readlane(f, 63);
}

// One block per image. R6-proven structure: staging + row-minima on 256
// threads; greedy zero-reduced-cost init; wave-0 deferred-dual SSP with
// all-f32 distances and column state in registers. R11 deltas (decision
// stream bit-identical to R6): (1) wave argmin via DPP value-min + index-min
// (VALU-speed, replaces 12 dependent ds_bpermutes); ties = smallest column,
// same as R6's lexicographic merge. (2) way[] kept in registers, flushed to
// LDS once per pass (augment only reads columns improved this pass).
extern "C" __global__ __launch_bounds__(NTH, 1)
void detr_hungarian_loss(const float* __restrict__ pc,    // [B,Q,14]
                         const float* __restrict__ pbx,   // [B,Q,4]
                         const int*   __restrict__ tl,    // [B,T]
                         const float* __restrict__ tbx,   // [B,T,4]
                         float* __restrict__ out)         // [1], poisoned 0xAA
{
    const int b   = blockIdx.x;
    const int tid = threadIdx.x;

    __shared__ float  sProb[Q_ * NCLS];   // softmax probs, classes 0..12
    __shared__ float  sLse[Q_];           // logsumexp per query (for CE)
    __shared__ float4 sPb4[Q_];           // predicted boxes
    __shared__ float4 sTb4[T_];           // target boxes
    __shared__ int    sLab[T_];           // target labels
    __shared__ float  sU[T_];             // row duals (f32)
    __shared__ int    sP[Q_];             // col -> row+1, 0 = free
    __shared__ int    sWay[Q_];           // parent cols (per pass); reused as tc[]
    __shared__ int    sAmin[T_];          // row -> argmin column
    __shared__ int    sFree[T_];
    __shared__ int    sNF;
    __shared__ int    sPred[T_];          // target t -> matched query
    __shared__ double sAcc[NWV];

    const float FINF = __builtin_inff();

    const float* pcb = pc  + (size_t)b * Q_ * NCLS1;
    const float* pbb = pbx + (size_t)b * Q_ * 4;
    const float* tbb = tbx + (size_t)b * T_ * 4;
    const int*   tlb = tl  + (size_t)b * T_;

    // ---- stage inputs + f32 softmax (same op order as jax.nn.softmax) ----
    for (int q = tid; q < Q_; q += NTH) {
        float x[NCLS1];
#pragma unroll
        for (int c = 0; c < NCLS1; ++c) x[c] = pcb[q * NCLS1 + c];
        float mx = x[0];
#pragma unroll
        for (int c = 1; c < NCLS1; ++c) mx = fmaxf(mx, x[c]);
        float ex[NCLS1];
        float sum = 0.f;
#pragma unroll
        for (int c = 0; c < NCLS1; ++c) { ex[c] = expf(x[c] - mx); sum += ex[c]; }
#pragma unroll
        for (int c = 0; c < NCLS; ++c) sProb[q * NCLS + c] = ex[c] / sum;
        sLse[q] = mx + logf(sum);
        sPb4[q] = reinterpret_cast<const float4*>(pbb)[q];
        sP[q] = 0;
    }
    for (int t = tid; t < T_; t += NTH) {
        sLab[t] = tlb[t];
        sTb4[t] = reinterpret_cast<const float4*>(tbb)[t];
    }
    __syncthreads();

    // ---- phase 1: row minima u[r] = min_j cost[r][j] + argmin column ----
    {
        const int r    = tid >> 1;        // 0..127, two threads per row
        const int half = tid & 1;
        const float4 t4  = sTb4[r];
        const int    lab = sLab[r];
        float bv = FINF;
        int   bj = Q_;
        const int q0 = half * (Q_ / 2);
        for (int q = q0; q < q0 + (Q_ / 2); ++q) {
            const float c = costQ(sPb4[q], t4, sProb[q * NCLS + lab]);
            if (c < bv) { bv = c; bj = q; }
        }
        const float ov = __shfl_xor(bv, 1);
        const int   oj = __shfl_xor(bj, 1);
        if (ov < bv || (ov == bv && oj < bj)) { bv = ov; bj = oj; }
        if (half == 0) { sU[r] = bv; sAmin[r] = bj; }
    }
    __syncthreads();

    // ---- greedy zero-reduced-cost assignment (R6-identical, serial) ----
    if (tid == 0) {
        int nf = 0;
        for (int r = 0; r < T_; ++r) {
            const int j = sAmin[r];
            if (sP[j] == 0) sP[j] = r + 1;
            else            sFree[nf++] = r;
        }
        sNF = nf;
    }
    __syncthreads();

    // ============ wave 0 only: deferred-dual SSP ============
    if (tid < 64) {
        const int lane = tid;
        const unsigned validMask = (lane < (Q_ - 64 * (NK - 1))) ? ((1u << NK) - 1u)
                                                                 : ((1u << (NK - 1)) - 1u);
        float4 pbr[NK];                   // owned predicted boxes
        float  v[NK];                     // owned column duals
#pragma unroll
        for (int k = 0; k < NK; ++k) {
            const int q = (k << 6) + lane;
            pbr[k] = (q < Q_) ? sPb4[q] : make_float4(0.f, 0.f, 0.f, 0.f);
            v[k] = 0.f;
        }
        const int nf = sNF;

        for (int fi = 0; fi < nf; ++fi) {
            const int rf = sFree[fi];
            float minv[NK];
            int   way[NK];
#pragma unroll
            for (int k = 0; k < NK; ++k) { minv[k] = FINF; way[k] = -1; }
            unsigned usedM   = ~validMask;
            unsigned poppedM = 0;
            int   i0row = rf;
            float dcur  = 0.f;
            int   jprev = -1;             // root marker
            float dT = 0.f; int jT = -1;

            for (int it = 0; it < 200; ++it) {
                const float  u0   = sU[i0row];
                const float4 t4   = sTb4[i0row];
                const int    lab  = sLab[i0row];
                const float  base = dcur - u0;

                float bestv = FINF;
                int   bestq = 1 << 29;
#pragma unroll
                for (int k = 0; k < NK; ++k) {
                    if (!((usedM >> k) & 1u)) {
                        const int   q    = (k << 6) + lane;
                        const float cost = costQ(pbr[k], t4, sProb[q * NCLS + lab]);
                        const float cur  = base + (cost - v[k]);   // R6 association
                        if (cur < minv[k]) { minv[k] = cur; way[k] = jprev; }
                        if (minv[k] < bestv) { bestv = minv[k]; bestq = q; }
                    }
                }
                // DPP wave argmin: exact min value, then smallest column among
                // value-ties (== R6's (value,col) lexicographic tie-break).
                const float winv = waveMinF32(bestv);
                const int   cand = (bestv == winv) ? bestq : 0x7fffffff;
                const int   winq = waveMinI32(cand);

                if ((winq & 63) == lane) usedM |= 1u << (winq >> 6);  // freeze
                const int rowm = sP[winq];
                __builtin_amdgcn_wave_barrier();
                if (rowm == 0) { dT = winv; jT = winq; break; }   // free col: done
                if ((winq & 63) == lane) poppedM |= 1u << (winq >> 6);
                jprev = winq; i0row = rowm - 1; dcur = winv;
            }

            // flush way regs (augment only reads cols improved this pass)
#pragma unroll
            for (int k = 0; k < NK; ++k) {
                if ((validMask >> k) & 1u) sWay[(k << 6) + lane] = way[k];
            }
            // deferred dual updates (== e-maxx incremental totals), pre-augment
#pragma unroll
            for (int k = 0; k < NK; ++k) {
                if ((poppedM >> k) & 1u) {
                    const int q   = (k << 6) + lane;
                    const int row = sP[q] - 1;        // distinct rows, no race
                    sU[row] += dT - minv[k];
                    v[k]    += minv[k] - dT;
                }
            }
            if (lane == 0) sU[rf] += dT;
            __builtin_amdgcn_wave_barrier();
            if (lane == 0 && jT >= 0) {                // augment along parents
                int jj = jT, guard = 0;
                while (guard++ < 200) {
                    const int jp = sWay[jj];
                    if (jp < 0) { sP[jj] = rf + 1; break; }
                    sP[jj] = sP[jp];
                    jj = jp;
                }
            }
            __builtin_amdgcn_wave_barrier();
        }
    }
    __syncthreads();

    // ---- extract matching: pred query for each target ----
    for (int q = tid; q < Q_; q += NTH) {
        const int pi = sP[q];
        if (pi > 0) sPred[pi - 1] = q;
    }
    __syncthreads();

    // ---- tc[] (reuse sWay): NUM_CLASSES default, matched queries get label ----
    int* sTc = sWay;
    for (int q = tid; q < Q_; q += NTH) sTc[q] = NCLS;
    __syncthreads();
    for (int t = tid; t < T_; t += NTH) sTc[sPred[t]] = sLab[t];  // sPred distinct
    __syncthreads();

    // ---- weighted CE over all queries ----
    double swn = 0.0, sw = 0.0;
    for (int q = tid; q < Q_; q += NTH) {
        const int   c   = sTc[q];
        const float xv  = pcb[q * NCLS1 + c];
        const float nll = sLse[q] - xv;              // -log_softmax[tc]
        const double w  = (c == NCLS) ? (double)0.05f : 1.0;
        swn += w * (double)nll;
        sw  += w;
    }

    // ---- bbox L1 + GIoU over matched pairs ----
    double l1s = 0.0, gs = 0.0;
    for (int t = tid; t < T_; t += NTH) {
        const int q = sPred[t];
        const float4 p4 = sPb4[q];
        const float4 t4 = sTb4[t];
        l1s += (double)fabsf(p4.x - t4.x) + (double)fabsf(p4.y - t4.y)
             + (double)fabsf(p4.z - t4.z) + (double)fabsf(p4.w - t4.w);
        const float ax1 = p4.x - 0.5f * p4.z, ay1 = p4.y - 0.5f * p4.w;
        const float ax2 = p4.x + 0.5f * p4.z, ay2 = p4.y + 0.5f * p4.w;
        const float bx1 = t4.x - 0.5f * t4.z, by1 = t4.y - 0.5f * t4.w;
        const float bx2 = t4.x + 0.5f * t4.z, by2 = t4.y + 0.5f * t4.w;
        const double a1 = (double)(ax2 - ax1) * (double)(ay2 - ay1);
        const double a2 = (double)(bx2 - bx1) * (double)(by2 - by1);
        const double ltx = fmax((double)ax1, (double)bx1);
        const double lty = fmax((double)ay1, (double)by1);
        const double rbx = fmin((double)ax2, (double)bx2);
        const double rby = fmin((double)ay2, (double)by2);
        const double iw = fmax(rbx - ltx, 0.0), ih = fmax(rby - lty, 0.0);
        const double inter = iw * ih;
        const double uni   = a1 + a2 - inter;
        const double iou   = inter / uni;
        const double cx1 = fmin((double)ax1, (double)bx1);
        const double cy1 = fmin((double)ay1, (double)by1);
        const double cx2 = fmax((double)ax2, (double)bx2);
        const double cy2 = fmax((double)ay2, (double)by2);
        const double ac  = (cx2 - cx1) * (cy2 - cy1);
        const double giou = iou - (ac - uni) / ac;
        gs += 1.0 - giou;
    }

    const double swnT = blockSum(swn, sAcc, tid);
    const double swT  = blockSum(sw,  sAcc, tid);
    const double l1T  = blockSum(l1s, sAcc, tid);
    const double gsT  = blockSum(gs,  sAcc, tid);
    if (tid == 0) {
        const double cls = swnT / swT;
        const double bb  = 5.0 * (l1T / (double)(T_ * 4)) + 2.0 * (gsT / (double)T_);
        const double mine = (cls + bb) / 8192.0;
        // fused finalize: CAS converts the 0xAA poison to 0.0 exactly once
        // (each block CASes before its own add; no spin), then atomic f32 sum.
        atomicCAS((unsigned int*)out, 0xAAAAAAAAu, 0u);
        atomicAdd(out, (float)mine);
    }
}

extern "C" void kernel_launch(void* const* d_in, const int* in_sizes, int n_in,
                              void* d_out, int out_size, void* d_ws, size_t ws_size,
                              hipStream_t stream) {
    const float* pc  = (const float*)d_in[0];   // predicted_class [64,900,14]
    const float* pbx = (const float*)d_in[1];   // predicted_bbox  [64,900,4]
    const int*   tl  = (const int*)  d_in[2];   // target_labels   [64,128]
    const float* tbx = (const float*)d_in[3];   // target_boxes    [64,128,4]
    (void)in_sizes; (void)n_in; (void)out_size; (void)d_ws; (void)ws_size;

    detr_hungarian_loss<<<dim3(B_), dim3(NTH), 0, stream>>>(pc, pbx, tl, tbx,
                                                            (float*)d_out);
}